// Round 1
// baseline (410.828 us; speedup 1.0000x reference)
//
#include <hip/hip_runtime.h>
#include <stdint.h>

#define Bb   2
#define Tt   2048
#define Cc_  2048
#define Hh   16
#define Dd   128
#define Mm_  4096            // B*T
#define N1   6144            // 3*C
#define EPSf 1.1920929e-07f
#define SCALE (1.0f/128.0f)  // reference uses 1/D, not 1/sqrt(D)

typedef __bf16 bf16;
typedef __attribute__((ext_vector_type(8))) __bf16 bf16x8;
typedef __attribute__((ext_vector_type(4))) float  f32x4;

// ---- async global->LDS, width 16. LDS dest = wave-uniform base + lane*16.
__device__ __forceinline__ void gl_lds16(const bf16* g, bf16* l) {
  __builtin_amdgcn_global_load_lds(
      (const __attribute__((address_space(1))) unsigned int*)g,
      (__attribute__((address_space(3))) unsigned int*)l, 16, 0, 0);
}

// ------------------------------------------------------------------ cvt x->bf16
__global__ __launch_bounds__(256) void cvt_bf16(const float* __restrict__ in,
                                                bf16* __restrict__ out, int n) {
  int i = (blockIdx.x * 256 + threadIdx.x) * 4;
  if (i >= n) return;
  float4 v = *(const float4*)(in + i);
  union { bf16 h[4]; uint2 u; } o;
  o.h[0] = (bf16)v.x; o.h[1] = (bf16)v.y; o.h[2] = (bf16)v.z; o.h[3] = (bf16)v.w;
  *(uint2*)(out + i) = o.u;
}

// -------------------------------------------- transpose+convert: [R][Cc]f32 -> [Cc][R]bf16
__global__ __launch_bounds__(256) void transpose_cvt(const float* __restrict__ in,
                                                     bf16* __restrict__ out,
                                                     int R, int Cc) {
  __shared__ float tile[64][65];
  int c0 = blockIdx.x * 64, r0 = blockIdx.y * 64;
  int tid = threadIdx.x;
#pragma unroll
  for (int j = 0; j < 16; ++j) {
    int idx = tid + j * 256;
    int r = idx >> 6, c = idx & 63;
    tile[r][c] = in[(size_t)(r0 + r) * Cc + c0 + c];
  }
  __syncthreads();
#pragma unroll
  for (int j = 0; j < 16; ++j) {
    int idx = tid + j * 256;
    int rr = idx & 63, cc = idx >> 6;
    out[(size_t)(c0 + cc) * R + r0 + rr] = (bf16)tile[rr][cc];
  }
}

// ----------------------------------- V transpose: [bh][T][D] -> [bh][D][T] bf16
__global__ __launch_bounds__(256) void vtrans(const bf16* __restrict__ V,
                                              bf16* __restrict__ Vt_) {
  __shared__ bf16 tile[64][72];
  int bh = blockIdx.z, t0 = blockIdx.x * 64, d0 = blockIdx.y * 64;
  int tid = threadIdx.x;
#pragma unroll
  for (int j = 0; j < 2; ++j) {
    int idx = (j * 256 + tid) * 8;
    int r = idx >> 6, c = idx & 63;
    bf16x8 v = *(const bf16x8*)(V + ((size_t)bh * Tt + t0 + r) * Dd + d0 + c);
#pragma unroll
    for (int e = 0; e < 8; ++e) tile[r][c + e] = v[e];
  }
  __syncthreads();
#pragma unroll
  for (int j = 0; j < 2; ++j) {
    int idx = (j * 256 + tid) * 8;
    int dd = idx >> 6, tt = idx & 63;
    bf16x8 v;
#pragma unroll
    for (int e = 0; e < 8; ++e) v[e] = tile[tt + e][dd];
    *(bf16x8*)(Vt_ + ((size_t)bh * Dd + d0 + dd) * Tt + t0 + tt) = v;
  }
}

// ------------------------------------------------------------------ GEMM 128^2
// C[M][N] = A[M][K] * Bt[N][K]^T, bf16 in, OutT out. 128x128 tile, BK=64.
// Kept for the proj GEMM (N=2048 -> 512 blocks = 2 rounds at good occupancy).
template <typename OutT>
__global__ __launch_bounds__(256) void gemm_bf16(const bf16* __restrict__ A,
                                                 const bf16* __restrict__ Bt,
                                                 OutT* __restrict__ Cm,
                                                 int Nn, int Kk) {
  __shared__ __align__(16) bf16 As[128 * 64];
  __shared__ __align__(16) bf16 Bs[128 * 64];
  const int tid = threadIdx.x;
  const int wave = tid >> 6, lane = tid & 63;
  const int quad = lane >> 4, li = lane & 15;
  const int wm = wave >> 1, wn = wave & 1;
  const int m0 = blockIdx.y * 128, n0 = blockIdx.x * 128;

  f32x4 acc[4][4] = {};

  for (int kt = 0; kt < Kk; kt += 64) {
    __syncthreads();
#pragma unroll
    for (int j = 0; j < 4; ++j) {
      int c = j * 256 + tid;
      int r = c >> 3, cc = c & 7;
      int gc = ((cc ^ (r & 7)) << 3);
      gl_lds16(A + (size_t)(m0 + r) * Kk + kt + gc, &As[c * 8]);
      gl_lds16(Bt + (size_t)(n0 + r) * Kk + kt + gc, &Bs[c * 8]);
    }
    __syncthreads();
#pragma unroll
    for (int kc = 0; kc < 2; ++kc) {
      bf16x8 af[4], bfr[4];
#pragma unroll
      for (int t = 0; t < 4; ++t) {
        int rowa = wm * 64 + t * 16 + li;
        af[t] = *(const bf16x8*)&As[rowa * 64 + (((kc * 4 + quad) ^ (rowa & 7)) << 3)];
        int rowb = wn * 64 + t * 16 + li;
        bfr[t] = *(const bf16x8*)&Bs[rowb * 64 + (((kc * 4 + quad) ^ (rowb & 7)) << 3)];
      }
#pragma unroll
      for (int mi = 0; mi < 4; ++mi)
#pragma unroll
        for (int ni = 0; ni < 4; ++ni)
          acc[mi][ni] = __builtin_amdgcn_mfma_f32_16x16x32_bf16(af[mi], bfr[ni],
                                                                acc[mi][ni], 0, 0, 0);
    }
  }
#pragma unroll
  for (int mi = 0; mi < 4; ++mi) {
    int row = m0 + wm * 64 + mi * 16 + quad * 4;
#pragma unroll
    for (int ni = 0; ni < 4; ++ni) {
      int col = n0 + wn * 64 + ni * 16 + li;
#pragma unroll
      for (int r = 0; r < 4; ++r)
        Cm[(size_t)(row + r) * Nn + col] = (OutT)acc[mi][ni][r];
    }
  }
}

// ------------------------------------------------------------------ GEMM 256^2, 8-wave,
// 4 phases per K-tile (BK=64), counted vmcnt(4) once per tile (T2+T3+T4+T5).
// Requires M%256==0, N%256==0, K%64==0, (gridX*gridY)%8==0.
//
// Halves (aligned with the 2x4 wave grid so each phase's reads hit exactly one half):
//   A-half h = rows with bit6==h  (wave wm reads rows wm*128 + mi*16+li; mi<4 -> bit6=0)
//   B-half h = rows with bit5==h  (wave wn reads rows wn*64  + nj*16+li; nj<2 -> bit5=0)
// Stage schedule (1 half-tile = 2 gl_lds16/thread per phase):
//   P0: Blow(t+1)->nxt   P1: Ahigh(t+1)->nxt   P2: Alow(t+2)->cur   P3: Bhigh(t+2)->cur
// Same-buffer stages (P2,P3) land after that slot's last read (P0,P1) - barrier-separated.
// Boundary wait vmcnt(4) at end of P3: allows only {Alow(t+2),Bhigh(t+2)} in flight;
// everything tile t+1 needs (newest = Ahigh(t+1)@P1) is guaranteed resident.
__global__ __launch_bounds__(512, 2) void gemm256(const bf16* __restrict__ A,
                                                  const bf16* __restrict__ Bt,
                                                  bf16* __restrict__ Cm,
                                                  int Nn, int Kk) {
  __shared__ __align__(16) bf16 As[2][256 * 64];
  __shared__ __align__(16) bf16 Bs[2][256 * 64];
  const int tid = threadIdx.x;
  const int wave = tid >> 6, lane = tid & 63;
  const int quad = lane >> 4, li = lane & 15;
  const int wm = wave >> 2, wn = wave & 3;  // 2(M) x 4(N) wave grid

  // XCD-aware bijective swizzle (both call sites have nwg % 8 == 0)
  const int nwg = gridDim.x * gridDim.y;
  const int wg  = blockIdx.y * gridDim.x + blockIdx.x;
  const int swz = (wg & 7) * (nwg >> 3) + (wg >> 3);
  const int m0 = (swz / gridDim.x) * 256;
  const int n0 = (swz % gridDim.x) * 256;

  const int NT = Kk >> 6;
  const int lrow = lane >> 3;           // row within an 8-row segment
  const int lchk = (lane & 7) ^ lrow;   // pre-swizzled source chunk (row&7 == lrow)

  auto stageA = [&](int tt, int h, int cb) {
    int kt = (tt < NT ? tt : NT - 1) << 6;
#pragma unroll
    for (int j = 0; j < 2; ++j) {
      int seg = j * 8 + wave;
      int r0 = ((seg >> 3) << 7) + (h << 6) + ((seg & 7) << 3);
      gl_lds16(A + (size_t)(m0 + r0 + lrow) * Kk + kt + (lchk << 3),
               &As[cb][r0 * 64]);
    }
  };
  auto stageB = [&](int tt, int h, int cb) {
    int kt = (tt < NT ? tt : NT - 1) << 6;
#pragma unroll
    for (int j = 0; j < 2; ++j) {
      int seg = j * 8 + wave;
      int r0 = ((seg >> 2) << 6) + (h << 5) + ((seg & 3) << 3);
      gl_lds16(Bt + (size_t)(n0 + r0 + lrow) * Kk + kt + (lchk << 3),
               &Bs[cb][r0 * 64]);
    }
  };

  f32x4 acc[8][4] = {};
  bf16x8 afr[4][2], bfr[2][2];

  auto rdA = [&](int h, int cb) {
#pragma unroll
    for (int mi = 0; mi < 4; ++mi) {
      int r = wm * 128 + h * 64 + mi * 16 + li;
#pragma unroll
      for (int kc = 0; kc < 2; ++kc)
        afr[mi][kc] = *(const bf16x8*)&As[cb][r * 64 + (((kc * 4 + quad) ^ (r & 7)) << 3)];
    }
  };
  auto rdB = [&](int h, int cb) {
#pragma unroll
    for (int nj = 0; nj < 2; ++nj) {
      int r = wn * 64 + h * 32 + nj * 16 + li;
#pragma unroll
      for (int kc = 0; kc < 2; ++kc)
        bfr[nj][kc] = *(const bf16x8*)&Bs[cb][r * 64 + (((kc * 4 + quad) ^ (r & 7)) << 3)];
    }
  };
  auto mmac = [&](int mo, int no) {
    __builtin_amdgcn_s_setprio(1);
#pragma unroll
    for (int kc = 0; kc < 2; ++kc)
#pragma unroll
      for (int mi = 0; mi < 4; ++mi)
#pragma unroll
        for (int nj = 0; nj < 2; ++nj)
          acc[mo + mi][no + nj] = __builtin_amdgcn_mfma_f32_16x16x32_bf16(
              afr[mi][kc], bfr[nj][kc], acc[mo + mi][no + nj], 0, 0, 0);
    __builtin_amdgcn_s_setprio(0);
  };

  // prologue: tile0 (all 4 halves) + Alow(1), Bhigh(1). vmcnt(4) -> tile0 resident.
  stageA(0, 0, 0); stageB(0, 0, 0); stageB(0, 1, 0); stageA(0, 1, 0);
  stageA(1, 0, 1); stageB(1, 1, 1);
  asm volatile("s_waitcnt vmcnt(4)" ::: "memory");
  __builtin_amdgcn_s_barrier();

  for (int t = 0; t < NT; ++t) {
    const int cur = t & 1, nxt = cur ^ 1;
    // ---- P0: Alow x Blow
    rdA(0, cur); rdB(0, cur);
    stageB(t + 1, 0, nxt);
    __builtin_amdgcn_s_barrier();
    asm volatile("s_waitcnt lgkmcnt(0)" ::: "memory");
    __builtin_amdgcn_sched_barrier(0);
    mmac(0, 0);
    __builtin_amdgcn_s_barrier();
    // ---- P1: Alow x Bhigh
    rdB(1, cur);
    stageA(t + 1, 1, nxt);
    __builtin_amdgcn_s_barrier();
    asm volatile("s_waitcnt lgkmcnt(0)" ::: "memory");
    __builtin_amdgcn_sched_barrier(0);
    mmac(0, 2);
    __builtin_amdgcn_s_barrier();
    // ---- P2: Ahigh x Bhigh   (stage into cur-Alow: last read was P0)
    rdA(1, cur);
    stageA(t + 2, 0, cur);
    __builtin_amdgcn_s_barrier();
    asm volatile("s_waitcnt lgkmcnt(0)" ::: "memory");
    __builtin_amdgcn_sched_barrier(0);
    mmac(4, 2);
    __builtin_amdgcn_s_barrier();
    // ---- P3: Ahigh x Blow    (stage into cur-Bhigh: last read was P1)
    rdB(0, cur);
    stageB(t + 2, 1, cur);
    __builtin_amdgcn_s_barrier();
    asm volatile("s_waitcnt lgkmcnt(0)" ::: "memory");
    __builtin_amdgcn_sched_barrier(0);
    mmac(4, 0);
    asm volatile("s_waitcnt vmcnt(4)" ::: "memory");  // counted, never 0 in-loop
    __builtin_amdgcn_s_barrier();
  }
  // drain tail stages before LDS is released at endpgm
  asm volatile("s_waitcnt vmcnt(0)" ::: "memory");

#pragma unroll
  for (int mi = 0; mi < 8; ++mi) {
    int row = m0 + wm * 128 + mi * 16 + quad * 4;
#pragma unroll
    for (int nj = 0; nj < 4; ++nj) {
      int col = n0 + wn * 64 + nj * 16 + li;
#pragma unroll
      for (int r = 0; r < 4; ++r)
        Cm[(size_t)(row + r) * Nn + col] = (bf16)acc[mi][nj][r];
    }
  }
}

// ------------------------------------------- RMSNorm + RoPE + rearrange
__global__ __launch_bounds__(256) void norm_rope_rearrange(
    const bf16* __restrict__ qkv, const float* __restrict__ qw,
    const float* __restrict__ kw, bf16* __restrict__ Qg,
    bf16* __restrict__ Kg, bf16* __restrict__ Vg) {
  int unit = blockIdx.x * 4 + (threadIdx.x >> 6);  // (b*T + t)*H + h
  int lane = threadIdx.x & 63;
  int h = unit & 15;
  int bt = unit >> 4;
  int t = bt & 2047, b = bt >> 11;
  const bf16* base = qkv + (size_t)bt * N1 + h * Dd;
  float q1 = (float)base[lane], q2 = (float)base[lane + 64];
  float k1 = (float)base[Cc_ + lane], k2 = (float)base[Cc_ + lane + 64];
  float v1 = (float)base[2 * Cc_ + lane], v2 = (float)base[2 * Cc_ + lane + 64];
  float sq = q1 * q1 + q2 * q2;
  float sk = k1 * k1 + k2 * k2;
#pragma unroll
  for (int o = 1; o < 64; o <<= 1) { sq += __shfl_xor(sq, o); sk += __shfl_xor(sk, o); }
  float rq = rsqrtf(sq * (1.0f / 128.0f) + EPSf);
  float rk = rsqrtf(sk * (1.0f / 128.0f) + EPSf);
  q1 *= rq * qw[lane]; q2 *= rq * qw[lane + 64];
  k1 *= rk * kw[lane]; k2 *= rk * kw[lane + 64];
  float invf = exp2f((float)lane * (-19.9315685693241740f / 64.0f));
  float ang = (float)t * invf;
  float sn, cs;
  sincosf(ang, &sn, &cs);
  float qo1 = q1 * cs - q2 * sn, qo2 = q2 * cs + q1 * sn;
  float ko1 = k1 * cs - k2 * sn, ko2 = k2 * cs + k1 * sn;
  size_t o1 = ((size_t)(b * Hh + h) * Tt + t) * Dd + lane;
  Qg[o1] = (bf16)qo1; Qg[o1 + 64] = (bf16)qo2;
  Kg[o1] = (bf16)ko1; Kg[o1 + 64] = (bf16)ko2;
  Vg[o1] = (bf16)v1;  Vg[o1 + 64] = (bf16)v2;
}

// ------------------------------------------------------------------ attention
// Single q-tile per block, grid 32bh x 32qt (qt descending), 1024 blocks.
// Exact-bound softmax: q,k RMS-normed (w=1) + RoPE norm-preserving + scale
// 1/128 => |s| <= ~1.01 (Cauchy-Schwarz). No max tracking, no per-step
// reductions, no o-rescale; L accumulated per-lane, reduced ONCE at the end.
__global__ __launch_bounds__(256, 3) void attn(const bf16* __restrict__ Qg,
                                               const bf16* __restrict__ Kg,
                                               const bf16* __restrict__ VgT,
                                               bf16* __restrict__ Yg) {
  __shared__ __align__(16) bf16 Kl[64 * 128];
  __shared__ __align__(16) bf16 Vl[128 * 64];
  __shared__ __align__(16) bf16 Pl[4 * 16 * 72];
  const int bh = blockIdx.x;
  const int qt = (int)gridDim.y - 1 - (int)blockIdx.y;  // long blocks first
  const int b = bh >> 4, h = bh & 15;
  const int tid = threadIdx.x, wave = tid >> 6, lane = tid & 63;
  const int quad = lane >> 4, li = lane & 15;
  const int q0 = qt * 64;

  // Q fragments (A-layout) straight from global, held for whole block
  const bf16* Qbase = Qg + ((size_t)bh * Tt + q0 + wave * 16 + li) * Dd;
  bf16x8 qf[4];
#pragma unroll
  for (int kc = 0; kc < 4; ++kc) qf[kc] = *(const bf16x8*)(Qbase + kc * 32 + quad * 8);

  f32x4 o[8] = {};
  float L[4] = {};
  bf16* Pw = &Pl[wave * 16 * 72];

  for (int kt = 0; kt <= qt; ++kt) {
    const int k0 = kt * 64;
    __syncthreads();  // prev iter's LDS reads done
    // stage K tile [64 k][128 d], 16B-chunk XOR swizzle
#pragma unroll
    for (int j = 0; j < 4; ++j) {
      int c = j * 256 + tid;
      int r = c >> 4, cc = c & 15;
      gl_lds16(Kg + ((size_t)bh * Tt + k0 + r) * Dd + ((cc ^ (r & 7)) << 3), &Kl[c * 8]);
    }
    // stage V^T tile [128 d][64 k], swizzled
#pragma unroll
    for (int j = 0; j < 4; ++j) {
      int c = j * 256 + tid;
      int r = c >> 3, cc = c & 7;
      gl_lds16(VgT + ((size_t)bh * Dd + r) * Tt + k0 + ((cc ^ (r & 7)) << 3), &Vl[c * 8]);
    }
    __syncthreads();

    // QK^T
    f32x4 s4[4] = {};
#pragma unroll
    for (int nt = 0; nt < 4; ++nt) {
      int key = nt * 16 + li;
#pragma unroll
      for (int kc = 0; kc < 4; ++kc) {
        bf16x8 kf = *(const bf16x8*)&Kl[key * 128 + (((kc * 4 + quad) ^ (key & 7)) << 3)];
        s4[nt] = __builtin_amdgcn_mfma_f32_16x16x32_bf16(qf[kc], kf, s4[nt], 0, 0, 0);
      }
    }
    // exp (no max needed: |s|<=1.01), mask, per-lane L accumulate, pack P
    const bool diag = (kt == qt);
#pragma unroll
    for (int nt = 0; nt < 4; ++nt)
#pragma unroll
      for (int r = 0; r < 4; ++r) {
        float e = __expf(s4[nt][r] * SCALE);
        if (diag && (nt * 16 + li > wave * 16 + quad * 4 + r)) e = 0.f;
        L[r] += e;
        Pw[(quad * 4 + r) * 72 + nt * 16 + li] = (bf16)e;
      }
    // PV: o[16 q][128 d] += P[16][64] * V[64][128]
#pragma unroll
    for (int kc = 0; kc < 2; ++kc) {
      bf16x8 pf = *(const bf16x8*)&Pw[li * 72 + kc * 32 + quad * 8];
#pragma unroll
      for (int u = 0; u < 8; ++u) {
        bf16x8 vf = *(const bf16x8*)&Vl[(u * 16 + li) * 64 + (((kc * 4 + quad) ^ (li & 7)) << 3)];
        o[u] = __builtin_amdgcn_mfma_f32_16x16x32_bf16(pf, vf, o[u], 0, 0, 0);
      }
    }
  }

  // single final row-sum reduction (width 16) + normalize + write
  float inv[4];
#pragma unroll
  for (int r = 0; r < 4; ++r) {
    float s0 = L[r];
#pragma unroll
    for (int off = 1; off < 16; off <<= 1) s0 += __shfl_xor(s0, off);
    inv[r] = 1.0f / s0;
  }
  int trow = q0 + wave * 16 + quad * 4;
#pragma unroll
  for (int u = 0; u < 8; ++u) {
    int col = h * Dd + u * 16 + li;
#pragma unroll
    for (int r = 0; r < 4; ++r)
      Yg[(size_t)(b * Tt + trow + r) * Cc_ + col] = (bf16)(o[u][r] * inv[r]);
  }
}

// ------------------------------------------------------------------ launch
extern "C" void kernel_launch(void* const* d_in, const int* in_sizes, int n_in,
                              void* d_out, int out_size, void* d_ws, size_t ws_size,
                              hipStream_t stream) {
  const float* x      = (const float*)d_in[0];
  const float* w_qkv  = (const float*)d_in[1];
  const float* w_proj = (const float*)d_in[2];
  const float* qnw    = (const float*)d_in[3];
  const float* knw    = (const float*)d_in[4];
  float* out = (float*)d_out;

  // workspace partition (bf16 elements)
  bf16* xb     = (bf16*)d_ws;                   // dead after qkv GEMM
  bf16* wqkvT  = xb + (size_t)Mm_ * Cc_;
  bf16* wprojT = wqkvT + (size_t)N1 * Cc_;
  bf16* qkv    = wprojT + (size_t)Cc_ * Cc_;    // dead after norm_rope
  bf16* Qg     = qkv + (size_t)Mm_ * N1;
  bf16* Kg     = Qg + (size_t)Bb * Hh * Tt * Dd;
  bf16* Vg     = Kg + (size_t)Bb * Hh * Tt * Dd;
  bf16* VgT    = xb;    // alias: exactly xb's size
  bf16* Yg     = qkv;   // alias into qkv's region

  hipLaunchKernelGGL(cvt_bf16, dim3((Mm_ * Cc_ / 4) / 256), dim3(256), 0, stream,
                     x, xb, Mm_ * Cc_);
  hipLaunchKernelGGL(transpose_cvt, dim3(N1 / 64, Cc_ / 64), dim3(256), 0, stream,
                     w_qkv, wqkvT, Cc_, N1);
  hipLaunchKernelGGL(transpose_cvt, dim3(Cc_ / 64, Cc_ / 64), dim3(256), 0, stream,
                     w_proj, wprojT, Cc_, Cc_);
  // QKV GEMM: 256^2 8-wave phase-pipelined (24x16 = 384 wg, %8==0)
  hipLaunchKernelGGL(gemm256, dim3(N1 / 256, Mm_ / 256), dim3(512), 0, stream,
                     xb, wqkvT, qkv, N1, Cc_);
  hipLaunchKernelGGL(norm_rope_rearrange, dim3(Bb * Tt * Hh / 4), dim3(256), 0, stream,
                     qkv, qnw, knw, Qg, Kg, Vg);
  hipLaunchKernelGGL(vtrans, dim3(Tt / 64, Dd / 64, Bb * Hh), dim3(256), 0, stream,
                     Vg, VgT);
  hipLaunchKernelGGL(attn, dim3(Bb * Hh, Tt / 64), dim3(256), 0, stream,
                     Qg, Kg, VgT, Yg);
  // proj GEMM stays on 128^2 (256^2 would give only 128 wg -> half the CUs idle)
  hipLaunchKernelGGL(gemm_bf16<float>, dim3(Cc_ / 128, Mm_ / 128), dim3(256), 0, stream,
                     Yg, wprojT, out, Cc_, Cc_);
}

// Round 2
// 391.040 us; speedup vs baseline: 1.0506x; 1.0506x over previous
//
#include <hip/hip_runtime.h>
#include <stdint.h>

#define Bb   2
#define Tt   2048
#define Cc_  2048
#define Hh   16
#define Dd   128
#define Mm_  4096            // B*T
#define N1   6144            // 3*C
#define EPSf 1.1920929e-07f
#define SCALE (1.0f/128.0f)  // reference uses 1/D, not 1/sqrt(D)

typedef __bf16 bf16;
typedef __attribute__((ext_vector_type(8))) __bf16 bf16x8;
typedef __attribute__((ext_vector_type(4))) float  f32x4;

// ---- async global->LDS, width 16. LDS dest = wave-uniform base + lane*16.
__device__ __forceinline__ void gl_lds16(const bf16* g, bf16* l) {
  __builtin_amdgcn_global_load_lds(
      (const __attribute__((address_space(1))) unsigned int*)g,
      (__attribute__((address_space(3))) unsigned int*)l, 16, 0, 0);
}

// ------------------------------------------------------------------ cvt x->bf16
__global__ __launch_bounds__(256) void cvt_bf16(const float* __restrict__ in,
                                                bf16* __restrict__ out, int n) {
  int i = (blockIdx.x * 256 + threadIdx.x) * 4;
  if (i >= n) return;
  float4 v = *(const float4*)(in + i);
  union { bf16 h[4]; uint2 u; } o;
  o.h[0] = (bf16)v.x; o.h[1] = (bf16)v.y; o.h[2] = (bf16)v.z; o.h[3] = (bf16)v.w;
  *(uint2*)(out + i) = o.u;
}

// -------------------------------------------- transpose+convert: [R][Cc]f32 -> [Cc][R]bf16
__global__ __launch_bounds__(256) void transpose_cvt(const float* __restrict__ in,
                                                     bf16* __restrict__ out,
                                                     int R, int Cc) {
  __shared__ float tile[64][65];
  int c0 = blockIdx.x * 64, r0 = blockIdx.y * 64;
  int tid = threadIdx.x;
#pragma unroll
  for (int j = 0; j < 16; ++j) {
    int idx = tid + j * 256;
    int r = idx >> 6, c = idx & 63;
    tile[r][c] = in[(size_t)(r0 + r) * Cc + c0 + c];
  }
  __syncthreads();
#pragma unroll
  for (int j = 0; j < 16; ++j) {
    int idx = tid + j * 256;
    int rr = idx & 63, cc = idx >> 6;
    out[(size_t)(c0 + cc) * R + r0 + rr] = (bf16)tile[rr][cc];
  }
}

// ----------------------------------- V transpose: [bh][T][D] -> [bh][D][T] bf16
__global__ __launch_bounds__(256) void vtrans(const bf16* __restrict__ V,
                                              bf16* __restrict__ Vt_) {
  __shared__ bf16 tile[64][72];
  int bh = blockIdx.z, t0 = blockIdx.x * 64, d0 = blockIdx.y * 64;
  int tid = threadIdx.x;
#pragma unroll
  for (int j = 0; j < 2; ++j) {
    int idx = (j * 256 + tid) * 8;
    int r = idx >> 6, c = idx & 63;
    bf16x8 v = *(const bf16x8*)(V + ((size_t)bh * Tt + t0 + r) * Dd + d0 + c);
#pragma unroll
    for (int e = 0; e < 8; ++e) tile[r][c + e] = v[e];
  }
  __syncthreads();
#pragma unroll
  for (int j = 0; j < 2; ++j) {
    int idx = (j * 256 + tid) * 8;
    int dd = idx >> 6, tt = idx & 63;
    bf16x8 v;
#pragma unroll
    for (int e = 0; e < 8; ++e) v[e] = tile[tt + e][dd];
    *(bf16x8*)(Vt_ + ((size_t)bh * Dd + d0 + dd) * Tt + t0 + tt) = v;
  }
}

// ------------------------------------------------------------------ GEMM 128^2
// C[M][N] = A[M][K] * Bt[N][K]^T, bf16 in, OutT out. 128x128 tile, BK=64.
// Kept for the proj GEMM (N=2048 -> 512 blocks = 2 rounds at good occupancy).
template <typename OutT>
__global__ __launch_bounds__(256) void gemm_bf16(const bf16* __restrict__ A,
                                                 const bf16* __restrict__ Bt,
                                                 OutT* __restrict__ Cm,
                                                 int Nn, int Kk) {
  __shared__ __align__(16) bf16 As[128 * 64];
  __shared__ __align__(16) bf16 Bs[128 * 64];
  const int tid = threadIdx.x;
  const int wave = tid >> 6, lane = tid & 63;
  const int quad = lane >> 4, li = lane & 15;
  const int wm = wave >> 1, wn = wave & 1;
  const int m0 = blockIdx.y * 128, n0 = blockIdx.x * 128;

  f32x4 acc[4][4] = {};

  for (int kt = 0; kt < Kk; kt += 64) {
    __syncthreads();
#pragma unroll
    for (int j = 0; j < 4; ++j) {
      int c = j * 256 + tid;
      int r = c >> 3, cc = c & 7;
      int gc = ((cc ^ (r & 7)) << 3);
      gl_lds16(A + (size_t)(m0 + r) * Kk + kt + gc, &As[c * 8]);
      gl_lds16(Bt + (size_t)(n0 + r) * Kk + kt + gc, &Bs[c * 8]);
    }
    __syncthreads();
#pragma unroll
    for (int kc = 0; kc < 2; ++kc) {
      bf16x8 af[4], bfr[4];
#pragma unroll
      for (int t = 0; t < 4; ++t) {
        int rowa = wm * 64 + t * 16 + li;
        af[t] = *(const bf16x8*)&As[rowa * 64 + (((kc * 4 + quad) ^ (rowa & 7)) << 3)];
        int rowb = wn * 64 + t * 16 + li;
        bfr[t] = *(const bf16x8*)&Bs[rowb * 64 + (((kc * 4 + quad) ^ (rowb & 7)) << 3)];
      }
#pragma unroll
      for (int mi = 0; mi < 4; ++mi)
#pragma unroll
        for (int ni = 0; ni < 4; ++ni)
          acc[mi][ni] = __builtin_amdgcn_mfma_f32_16x16x32_bf16(af[mi], bfr[ni],
                                                                acc[mi][ni], 0, 0, 0);
    }
  }
#pragma unroll
  for (int mi = 0; mi < 4; ++mi) {
    int row = m0 + wm * 64 + mi * 16 + quad * 4;
#pragma unroll
    for (int ni = 0; ni < 4; ++ni) {
      int col = n0 + wn * 64 + ni * 16 + li;
#pragma unroll
      for (int r = 0; r < 4; ++r)
        Cm[(size_t)(row + r) * Nn + col] = (OutT)acc[mi][ni][r];
    }
  }
}

// ------------------------------------------------------------------ GEMM 256^2, 8-wave,
// m201-template schedule: 4 phases per K-tile, 2 K-tiles per unrolled iter.
// Quadrant walk (A0,B0)->(A0,B1)->(A1,B1)->(A1,B0); BOTH B-half fragments held
// in registers -> reads/phase = 12,4,8,0 (24 b128/wave/K-tile, minimal).
// Stage order: P0: A1(t+1)->nxt, P1: A0(t+2)->cur, P2: B0(t+2)->cur,
//              P3: B1(t+2)->cur.  Each restage lands one barrier after that
// region's last LDS read (A0 last read P0, B0 read P0 (held), B1 read P1 (held),
// A1 of the OTHER buffer last read in its tile's P2).
// vmcnt(6) (= 3 half-tiles in flight) once per K-tile in pure-MFMA P3:
//   queue at end of tile t: [..., A1(t+1)@t.P0, A0(t+2)@t.P1, B0(t+2)@t.P2,
//   B1(t+2)@t.P3]; allowing newest 6 loads leaves exactly the t+2 stages in
//   flight -> everything tile t+1 reads is resident. Requires K%128==0.
__global__ __launch_bounds__(512, 2) void gemm256(const bf16* __restrict__ A,
                                                  const bf16* __restrict__ Bt,
                                                  bf16* __restrict__ Cm,
                                                  int Nn, int Kk) {
  __shared__ __align__(16) bf16 As[2][256 * 64];
  __shared__ __align__(16) bf16 Bs[2][256 * 64];
  const int tid = threadIdx.x;
  const int wave = tid >> 6, lane = tid & 63;
  const int quad = lane >> 4, li = lane & 15;
  const int wm = wave >> 2, wn = wave & 3;  // 2(M) x 4(N) wave grid

  // XCD-aware bijective swizzle (both call sites have nwg % 8 == 0)
  const int nwg = gridDim.x * gridDim.y;
  const int wg  = blockIdx.y * gridDim.x + blockIdx.x;
  const int swz = (wg & 7) * (nwg >> 3) + (wg >> 3);
  const int m0 = (swz / gridDim.x) * 256;
  const int n0 = (swz % gridDim.x) * 256;

  const int NT = Kk >> 6;
  const int lrow = lane >> 3;           // row within an 8-row segment
  const int lchk = (lane & 7) ^ lrow;   // pre-swizzled source chunk (row&7 == lrow)

  auto stageA = [&](int tt, int h, int cb) {
    int kt = (tt < NT ? tt : NT - 1) << 6;
#pragma unroll
    for (int j = 0; j < 2; ++j) {
      int seg = j * 8 + wave;
      int r0 = ((seg >> 3) << 7) + (h << 6) + ((seg & 7) << 3);
      gl_lds16(A + (size_t)(m0 + r0 + lrow) * Kk + kt + (lchk << 3),
               &As[cb][r0 * 64]);
    }
  };
  auto stageB = [&](int tt, int h, int cb) {
    int kt = (tt < NT ? tt : NT - 1) << 6;
#pragma unroll
    for (int j = 0; j < 2; ++j) {
      int seg = j * 8 + wave;
      int r0 = ((seg >> 2) << 6) + (h << 5) + ((seg & 3) << 3);
      gl_lds16(Bt + (size_t)(n0 + r0 + lrow) * Kk + kt + (lchk << 3),
               &Bs[cb][r0 * 64]);
    }
  };

  f32x4 acc[8][4] = {};
  bf16x8 afr[4][2], b0r[2][2], b1r[2][2];

  auto rdA = [&](int h, int cb) {
#pragma unroll
    for (int mi = 0; mi < 4; ++mi) {
      int r = wm * 128 + h * 64 + mi * 16 + li;
#pragma unroll
      for (int kc = 0; kc < 2; ++kc)
        afr[mi][kc] = *(const bf16x8*)&As[cb][r * 64 + (((kc * 4 + quad) ^ (r & 7)) << 3)];
    }
  };
  auto rdB = [&](int h, int cb, bf16x8 (&dst)[2][2]) {
#pragma unroll
    for (int nj = 0; nj < 2; ++nj) {
      int r = wn * 64 + h * 32 + nj * 16 + li;
#pragma unroll
      for (int kc = 0; kc < 2; ++kc)
        dst[nj][kc] = *(const bf16x8*)&Bs[cb][r * 64 + (((kc * 4 + quad) ^ (r & 7)) << 3)];
    }
  };
  auto mmac = [&](int mo, int no, bf16x8 (&b)[2][2]) {
    __builtin_amdgcn_s_setprio(1);
#pragma unroll
    for (int kc = 0; kc < 2; ++kc)
#pragma unroll
      for (int mi = 0; mi < 4; ++mi)
#pragma unroll
        for (int nj = 0; nj < 2; ++nj)
          acc[mo + mi][no + nj] = __builtin_amdgcn_mfma_f32_16x16x32_bf16(
              afr[mi][kc], b[nj][kc], acc[mo + mi][no + nj], 0, 0, 0);
    __builtin_amdgcn_s_setprio(0);
  };

  auto tile = [&](int t, int cur, int nxt) {
    // ---- P0: A0 x B0  (12 ds_reads; stage A1(t+1)->nxt)
    rdA(0, cur); rdB(0, cur, b0r);
    stageA(t + 1, 1, nxt);
    asm volatile("s_waitcnt lgkmcnt(8)" ::: "memory");  // throttle heavy phase
    __builtin_amdgcn_s_barrier();
    asm volatile("s_waitcnt lgkmcnt(0)" ::: "memory");
    __builtin_amdgcn_sched_barrier(0);
    mmac(0, 0, b0r);
    __builtin_amdgcn_s_barrier();
    // ---- P1: A0 x B1  (4 ds_reads; stage A0(t+2)->cur, last read was P0)
    rdB(1, cur, b1r);
    stageA(t + 2, 0, cur);
    __builtin_amdgcn_s_barrier();
    asm volatile("s_waitcnt lgkmcnt(0)" ::: "memory");
    __builtin_amdgcn_sched_barrier(0);
    mmac(0, 2, b1r);
    __builtin_amdgcn_s_barrier();
    // ---- P2: A1 x B1  (8 ds_reads; stage B0(t+2)->cur, B0 held in regs)
    rdA(1, cur);
    stageB(t + 2, 0, cur);
    __builtin_amdgcn_s_barrier();
    asm volatile("s_waitcnt lgkmcnt(0)" ::: "memory");
    __builtin_amdgcn_sched_barrier(0);
    mmac(4, 2, b1r);
    __builtin_amdgcn_s_barrier();
    // ---- P3: A1 x B0  (0 ds_reads; stage B1(t+2)->cur; counted vmcnt here)
    stageB(t + 2, 1, cur);
    __builtin_amdgcn_s_barrier();
    __builtin_amdgcn_sched_barrier(0);
    mmac(4, 0, b0r);
    asm volatile("s_waitcnt vmcnt(6)" ::: "memory");  // 3 half-tiles in flight
    __builtin_amdgcn_s_barrier();
  };

  // prologue: tile0 all 4 halves + tile1 {A0,B0,B1}; vmcnt(6) -> tile0 resident
  stageA(0, 0, 0); stageB(0, 0, 0); stageB(0, 1, 0); stageA(0, 1, 0);
  stageA(1, 0, 1); stageB(1, 0, 1); stageB(1, 1, 1);
  asm volatile("s_waitcnt vmcnt(6)" ::: "memory");
  __builtin_amdgcn_s_barrier();

  for (int t = 0; t < NT; t += 2) {   // K % 128 == 0
    tile(t, 0, 1);
    tile(t + 1, 1, 0);
  }
  // drain tail stages before LDS is released at endpgm
  asm volatile("s_waitcnt vmcnt(0)" ::: "memory");

#pragma unroll
  for (int mi = 0; mi < 8; ++mi) {
    int row = m0 + wm * 128 + mi * 16 + quad * 4;
#pragma unroll
    for (int nj = 0; nj < 4; ++nj) {
      int col = n0 + wn * 64 + nj * 16 + li;
#pragma unroll
      for (int r = 0; r < 4; ++r)
        Cm[(size_t)(row + r) * Nn + col] = (bf16)acc[mi][nj][r];
    }
  }
}

// ------------------------------------------- RMSNorm + RoPE + rearrange
__global__ __launch_bounds__(256) void norm_rope_rearrange(
    const bf16* __restrict__ qkv, const float* __restrict__ qw,
    const float* __restrict__ kw, bf16* __restrict__ Qg,
    bf16* __restrict__ Kg, bf16* __restrict__ Vg) {
  int unit = blockIdx.x * 4 + (threadIdx.x >> 6);  // (b*T + t)*H + h
  int lane = threadIdx.x & 63;
  int h = unit & 15;
  int bt = unit >> 4;
  int t = bt & 2047, b = bt >> 11;
  const bf16* base = qkv + (size_t)bt * N1 + h * Dd;
  float q1 = (float)base[lane], q2 = (float)base[lane + 64];
  float k1 = (float)base[Cc_ + lane], k2 = (float)base[Cc_ + lane + 64];
  float v1 = (float)base[2 * Cc_ + lane], v2 = (float)base[2 * Cc_ + lane + 64];
  float sq = q1 * q1 + q2 * q2;
  float sk = k1 * k1 + k2 * k2;
#pragma unroll
  for (int o = 1; o < 64; o <<= 1) { sq += __shfl_xor(sq, o); sk += __shfl_xor(sk, o); }
  float rq = rsqrtf(sq * (1.0f / 128.0f) + EPSf);
  float rk = rsqrtf(sk * (1.0f / 128.0f) + EPSf);
  q1 *= rq * qw[lane]; q2 *= rq * qw[lane + 64];
  k1 *= rk * kw[lane]; k2 *= rk * kw[lane + 64];
  float invf = exp2f((float)lane * (-19.9315685693241740f / 64.0f));
  float ang = (float)t * invf;
  float sn, cs;
  sincosf(ang, &sn, &cs);
  float qo1 = q1 * cs - q2 * sn, qo2 = q2 * cs + q1 * sn;
  float ko1 = k1 * cs - k2 * sn, ko2 = k2 * cs + k1 * sn;
  size_t o1 = ((size_t)(b * Hh + h) * Tt + t) * Dd + lane;
  Qg[o1] = (bf16)qo1; Qg[o1 + 64] = (bf16)qo2;
  Kg[o1] = (bf16)ko1; Kg[o1 + 64] = (bf16)ko2;
  Vg[o1] = (bf16)v1;  Vg[o1 + 64] = (bf16)v2;
}

// ------------------------------------------------------------------ attention
// Single q-tile per block, grid 32bh x 32qt (qt descending), 1024 blocks.
// Exact-bound softmax: q,k RMS-normed (w=1) + RoPE norm-preserving + scale
// 1/128 => |s| <= ~1.01 (Cauchy-Schwarz). No max tracking, no per-step
// reductions, no o-rescale; L accumulated per-lane, reduced ONCE at the end.
__global__ __launch_bounds__(256, 3) void attn(const bf16* __restrict__ Qg,
                                               const bf16* __restrict__ Kg,
                                               const bf16* __restrict__ VgT,
                                               bf16* __restrict__ Yg) {
  __shared__ __align__(16) bf16 Kl[64 * 128];
  __shared__ __align__(16) bf16 Vl[128 * 64];
  __shared__ __align__(16) bf16 Pl[4 * 16 * 72];
  const int bh = blockIdx.x;
  const int qt = (int)gridDim.y - 1 - (int)blockIdx.y;  // long blocks first
  const int b = bh >> 4, h = bh & 15;
  const int tid = threadIdx.x, wave = tid >> 6, lane = tid & 63;
  const int quad = lane >> 4, li = lane & 15;
  const int q0 = qt * 64;

  // Q fragments (A-layout) straight from global, held for whole block
  const bf16* Qbase = Qg + ((size_t)bh * Tt + q0 + wave * 16 + li) * Dd;
  bf16x8 qf[4];
#pragma unroll
  for (int kc = 0; kc < 4; ++kc) qf[kc] = *(const bf16x8*)(Qbase + kc * 32 + quad * 8);

  f32x4 o[8] = {};
  float L[4] = {};
  bf16* Pw = &Pl[wave * 16 * 72];

  for (int kt = 0; kt <= qt; ++kt) {
    const int k0 = kt * 64;
    __syncthreads();  // prev iter's LDS reads done
    // stage K tile [64 k][128 d], 16B-chunk XOR swizzle
#pragma unroll
    for (int j = 0; j < 4; ++j) {
      int c = j * 256 + tid;
      int r = c >> 4, cc = c & 15;
      gl_lds16(Kg + ((size_t)bh * Tt + k0 + r) * Dd + ((cc ^ (r & 7)) << 3), &Kl[c * 8]);
    }
    // stage V^T tile [128 d][64 k], swizzled
#pragma unroll
    for (int j = 0; j < 4; ++j) {
      int c = j * 256 + tid;
      int r = c >> 3, cc = c & 7;
      gl_lds16(VgT + ((size_t)bh * Dd + r) * Tt + k0 + ((cc ^ (r & 7)) << 3), &Vl[c * 8]);
    }
    __syncthreads();

    // QK^T
    f32x4 s4[4] = {};
#pragma unroll
    for (int nt = 0; nt < 4; ++nt) {
      int key = nt * 16 + li;
#pragma unroll
      for (int kc = 0; kc < 4; ++kc) {
        bf16x8 kf = *(const bf16x8*)&Kl[key * 128 + (((kc * 4 + quad) ^ (key & 7)) << 3)];
        s4[nt] = __builtin_amdgcn_mfma_f32_16x16x32_bf16(qf[kc], kf, s4[nt], 0, 0, 0);
      }
    }
    // exp (no max needed: |s|<=1.01), mask, per-lane L accumulate, pack P
    const bool diag = (kt == qt);
#pragma unroll
    for (int nt = 0; nt < 4; ++nt)
#pragma unroll
      for (int r = 0; r < 4; ++r) {
        float e = __expf(s4[nt][r] * SCALE);
        if (diag && (nt * 16 + li > wave * 16 + quad * 4 + r)) e = 0.f;
        L[r] += e;
        Pw[(quad * 4 + r) * 72 + nt * 16 + li] = (bf16)e;
      }
    // PV: o[16 q][128 d] += P[16][64] * V[64][128]
#pragma unroll
    for (int kc = 0; kc < 2; ++kc) {
      bf16x8 pf = *(const bf16x8*)&Pw[li * 72 + kc * 32 + quad * 8];
#pragma unroll
      for (int u = 0; u < 8; ++u) {
        bf16x8 vf = *(const bf16x8*)&Vl[(u * 16 + li) * 64 + (((kc * 4 + quad) ^ (li & 7)) << 3)];
        o[u] = __builtin_amdgcn_mfma_f32_16x16x32_bf16(pf, vf, o[u], 0, 0, 0);
      }
    }
  }

  // single final row-sum reduction (width 16) + normalize + write
  float inv[4];
#pragma unroll
  for (int r = 0; r < 4; ++r) {
    float s0 = L[r];
#pragma unroll
    for (int off = 1; off < 16; off <<= 1) s0 += __shfl_xor(s0, off);
    inv[r] = 1.0f / s0;
  }
  int trow = q0 + wave * 16 + quad * 4;
#pragma unroll
  for (int u = 0; u < 8; ++u) {
    int col = h * Dd + u * 16 + li;
#pragma unroll
    for (int r = 0; r < 4; ++r)
      Yg[(size_t)(b * Tt + trow + r) * Cc_ + col] = (bf16)(o[u][r] * inv[r]);
  }
}

// ------------------------------------------------------------------ launch
extern "C" void kernel_launch(void* const* d_in, const int* in_sizes, int n_in,
                              void* d_out, int out_size, void* d_ws, size_t ws_size,
                              hipStream_t stream) {
  const float* x      = (const float*)d_in[0];
  const float* w_qkv  = (const float*)d_in[1];
  const float* w_proj = (const float*)d_in[2];
  const float* qnw    = (const float*)d_in[3];
  const float* knw    = (const float*)d_in[4];
  float* out = (float*)d_out;

  // workspace partition (bf16 elements)
  bf16* xb     = (bf16*)d_ws;                   // dead after qkv GEMM
  bf16* wqkvT  = xb + (size_t)Mm_ * Cc_;
  bf16* wprojT = wqkvT + (size_t)N1 * Cc_;
  bf16* qkv    = wprojT + (size_t)Cc_ * Cc_;    // dead after norm_rope
  bf16* Qg     = qkv + (size_t)Mm_ * N1;
  bf16* Kg     = Qg + (size_t)Bb * Hh * Tt * Dd;
  bf16* Vg     = Kg + (size_t)Bb * Hh * Tt * Dd;
  bf16* VgT    = xb;    // alias: exactly xb's size
  bf16* Yg     = qkv;   // alias into qkv's region

  hipLaunchKernelGGL(cvt_bf16, dim3((Mm_ * Cc_ / 4) / 256), dim3(256), 0, stream,
                     x, xb, Mm_ * Cc_);
  hipLaunchKernelGGL(transpose_cvt, dim3(N1 / 64, Cc_ / 64), dim3(256), 0, stream,
                     w_qkv, wqkvT, Cc_, N1);
  hipLaunchKernelGGL(transpose_cvt, dim3(Cc_ / 64, Cc_ / 64), dim3(256), 0, stream,
                     w_proj, wprojT, Cc_, Cc_);
  // QKV GEMM: 256^2 8-wave, m201-template phase schedule (24x16 = 384 wg)
  hipLaunchKernelGGL(gemm256, dim3(N1 / 256, Mm_ / 256), dim3(512), 0, stream,
                     xb, wqkvT, qkv, N1, Cc_);
  hipLaunchKernelGGL(norm_rope_rearrange, dim3(Bb * Tt * Hh / 4), dim3(256), 0, stream,
                     qkv, qnw, knw, Qg, Kg, Vg);
  hipLaunchKernelGGL(vtrans, dim3(Tt / 64, Dd / 64, Bb * Hh), dim3(256), 0, stream,
                     Vg, VgT);
  hipLaunchKernelGGL(attn, dim3(Bb * Hh, Tt / 64), dim3(256), 0, stream,
                     Qg, Kg, VgT, Yg);
  // proj GEMM stays on 128^2 (256^2 would give only 128 wg -> half the CUs idle)
  hipLaunchKernelGGL(gemm_bf16<float>, dim3(Cc_ / 128, Mm_ / 128), dim3(256), 0, stream,
                     Yg, wprojT, out, Cc_, Cc_);
}

// Round 3
// 381.025 us; speedup vs baseline: 1.0782x; 1.0263x over previous
//
#include <hip/hip_runtime.h>
#include <stdint.h>

#define Bb   2
#define Tt   2048
#define Cc_  2048
#define Hh   16
#define Dd   128
#define Mm_  4096            // B*T
#define N1   6144            // 3*C
#define EPSf 1.1920929e-07f
#define SCALE (1.0f/128.0f)  // reference uses 1/D, not 1/sqrt(D)

typedef __bf16 bf16;
typedef __attribute__((ext_vector_type(8))) __bf16 bf16x8;
typedef __attribute__((ext_vector_type(4))) float  f32x4;

// ---- async global->LDS, width 16. LDS dest = wave-uniform base + lane*16.
__device__ __forceinline__ void gl_lds16(const bf16* g, bf16* l) {
  __builtin_amdgcn_global_load_lds(
      (const __attribute__((address_space(1))) unsigned int*)g,
      (__attribute__((address_space(3))) unsigned int*)l, 16, 0, 0);
}

// ------------------------------------------------------------------ cvt x->bf16
__global__ __launch_bounds__(256) void cvt_bf16(const float* __restrict__ in,
                                                bf16* __restrict__ out, int n) {
  int i = (blockIdx.x * 256 + threadIdx.x) * 4;
  if (i >= n) return;
  float4 v = *(const float4*)(in + i);
  union { bf16 h[4]; uint2 u; } o;
  o.h[0] = (bf16)v.x; o.h[1] = (bf16)v.y; o.h[2] = (bf16)v.z; o.h[3] = (bf16)v.w;
  *(uint2*)(out + i) = o.u;
}

// -------------------------------------------- transpose+convert: [R][Cc]f32 -> [Cc][R]bf16
__global__ __launch_bounds__(256) void transpose_cvt(const float* __restrict__ in,
                                                     bf16* __restrict__ out,
                                                     int R, int Cc) {
  __shared__ float tile[64][65];
  int c0 = blockIdx.x * 64, r0 = blockIdx.y * 64;
  int tid = threadIdx.x;
#pragma unroll
  for (int j = 0; j < 16; ++j) {
    int idx = tid + j * 256;
    int r = idx >> 6, c = idx & 63;
    tile[r][c] = in[(size_t)(r0 + r) * Cc + c0 + c];
  }
  __syncthreads();
#pragma unroll
  for (int j = 0; j < 16; ++j) {
    int idx = tid + j * 256;
    int rr = idx & 63, cc = idx >> 6;
    out[(size_t)(c0 + cc) * R + r0 + rr] = (bf16)tile[rr][cc];
  }
}

// ----------------------------------- V transpose: [bh][T][D] -> [bh][D][T] bf16
__global__ __launch_bounds__(256) void vtrans(const bf16* __restrict__ V,
                                              bf16* __restrict__ Vt_) {
  __shared__ bf16 tile[64][72];
  int bh = blockIdx.z, t0 = blockIdx.x * 64, d0 = blockIdx.y * 64;
  int tid = threadIdx.x;
#pragma unroll
  for (int j = 0; j < 2; ++j) {
    int idx = (j * 256 + tid) * 8;
    int r = idx >> 6, c = idx & 63;
    bf16x8 v = *(const bf16x8*)(V + ((size_t)bh * Tt + t0 + r) * Dd + d0 + c);
#pragma unroll
    for (int e = 0; e < 8; ++e) tile[r][c + e] = v[e];
  }
  __syncthreads();
#pragma unroll
  for (int j = 0; j < 2; ++j) {
    int idx = (j * 256 + tid) * 8;
    int dd = idx >> 6, tt = idx & 63;
    bf16x8 v;
#pragma unroll
    for (int e = 0; e < 8; ++e) v[e] = tile[tt + e][dd];
    *(bf16x8*)(Vt_ + ((size_t)bh * Dd + d0 + dd) * Tt + t0 + tt) = v;
  }
}

// ------------------------------------------------------------------ GEMM
// C[M][N] = A[M][K] * Bt[N][K]^T, bf16 in, OutT out. 128x128 tile, BK=64.
// Proven 912-TF structure (m97-class). Used for BOTH GEMMs.
template <typename OutT>
__global__ __launch_bounds__(256) void gemm_bf16(const bf16* __restrict__ A,
                                                 const bf16* __restrict__ Bt,
                                                 OutT* __restrict__ Cm,
                                                 int Nn, int Kk) {
  __shared__ __align__(16) bf16 As[128 * 64];
  __shared__ __align__(16) bf16 Bs[128 * 64];
  const int tid = threadIdx.x;
  const int wave = tid >> 6, lane = tid & 63;
  const int quad = lane >> 4, li = lane & 15;
  const int wm = wave >> 1, wn = wave & 1;
  const int m0 = blockIdx.y * 128, n0 = blockIdx.x * 128;

  f32x4 acc[4][4] = {};

  for (int kt = 0; kt < Kk; kt += 64) {
    __syncthreads();
#pragma unroll
    for (int j = 0; j < 4; ++j) {
      int c = j * 256 + tid;
      int r = c >> 3, cc = c & 7;
      int gc = ((cc ^ (r & 7)) << 3);
      gl_lds16(A + (size_t)(m0 + r) * Kk + kt + gc, &As[c * 8]);
      gl_lds16(Bt + (size_t)(n0 + r) * Kk + kt + gc, &Bs[c * 8]);
    }
    __syncthreads();
#pragma unroll
    for (int kc = 0; kc < 2; ++kc) {
      bf16x8 af[4], bfr[4];
#pragma unroll
      for (int t = 0; t < 4; ++t) {
        int rowa = wm * 64 + t * 16 + li;
        af[t] = *(const bf16x8*)&As[rowa * 64 + (((kc * 4 + quad) ^ (rowa & 7)) << 3)];
        int rowb = wn * 64 + t * 16 + li;
        bfr[t] = *(const bf16x8*)&Bs[rowb * 64 + (((kc * 4 + quad) ^ (rowb & 7)) << 3)];
      }
#pragma unroll
      for (int mi = 0; mi < 4; ++mi)
#pragma unroll
        for (int ni = 0; ni < 4; ++ni)
          acc[mi][ni] = __builtin_amdgcn_mfma_f32_16x16x32_bf16(af[mi], bfr[ni],
                                                                acc[mi][ni], 0, 0, 0);
    }
  }
#pragma unroll
  for (int mi = 0; mi < 4; ++mi) {
    int row = m0 + wm * 64 + mi * 16 + quad * 4;
#pragma unroll
    for (int ni = 0; ni < 4; ++ni) {
      int col = n0 + wn * 64 + ni * 16 + li;
#pragma unroll
      for (int r = 0; r < 4; ++r)
        Cm[(size_t)(row + r) * Nn + col] = (OutT)acc[mi][ni][r];
    }
  }
}

// ------------------------------------------- RMSNorm + RoPE + rearrange
__global__ __launch_bounds__(256) void norm_rope_rearrange(
    const bf16* __restrict__ qkv, const float* __restrict__ qw,
    const float* __restrict__ kw, bf16* __restrict__ Qg,
    bf16* __restrict__ Kg, bf16* __restrict__ Vg) {
  int unit = blockIdx.x * 4 + (threadIdx.x >> 6);  // (b*T + t)*H + h
  int lane = threadIdx.x & 63;
  int h = unit & 15;
  int bt = unit >> 4;
  int t = bt & 2047, b = bt >> 11;
  const bf16* base = qkv + (size_t)bt * N1 + h * Dd;
  float q1 = (float)base[lane], q2 = (float)base[lane + 64];
  float k1 = (float)base[Cc_ + lane], k2 = (float)base[Cc_ + lane + 64];
  float v1 = (float)base[2 * Cc_ + lane], v2 = (float)base[2 * Cc_ + lane + 64];
  float sq = q1 * q1 + q2 * q2;
  float sk = k1 * k1 + k2 * k2;
#pragma unroll
  for (int o = 1; o < 64; o <<= 1) { sq += __shfl_xor(sq, o); sk += __shfl_xor(sk, o); }
  float rq = rsqrtf(sq * (1.0f / 128.0f) + EPSf);
  float rk = rsqrtf(sk * (1.0f / 128.0f) + EPSf);
  q1 *= rq * qw[lane]; q2 *= rq * qw[lane + 64];
  k1 *= rk * kw[lane]; k2 *= rk * kw[lane + 64];
  float invf = exp2f((float)lane * (-19.9315685693241740f / 64.0f));
  float ang = (float)t * invf;
  float sn, cs;
  sincosf(ang, &sn, &cs);
  float qo1 = q1 * cs - q2 * sn, qo2 = q2 * cs + q1 * sn;
  float ko1 = k1 * cs - k2 * sn, ko2 = k2 * cs + k1 * sn;
  size_t o1 = ((size_t)(b * Hh + h) * Tt + t) * Dd + lane;
  Qg[o1] = (bf16)qo1; Qg[o1 + 64] = (bf16)qo2;
  Kg[o1] = (bf16)ko1; Kg[o1 + 64] = (bf16)ko2;
  Vg[o1] = (bf16)v1;  Vg[o1 + 64] = (bf16)v2;
}

// ------------------------------------------------------------------ attention
// Single q-tile per block, grid 32bh x 32qt (qt descending), 1024 blocks.
// Exact-bound softmax: q,k RMS-normed (w=1) + RoPE norm-preserving + scale
// 1/128 => |s| <= ~1.01 (Cauchy-Schwarz). No max tracking, no o-rescale;
// L accumulated per-lane, reduced ONCE at the end.
//
// T14 async-staged pipeline (no LDS growth, occupancy stays 3/CU):
//   K(kt):  global->reg during iter kt-1 (latency under softmax+PV+barriers),
//           reg->LDS ds_write at top of iter kt (Kl free: last read = QK^T(kt-1),
//           two barriers back).
//   V(kt):  gl_lds issued at END of iter kt-1 (after PV-done barrier; Vl free),
//           latency hidden under ds_write-K + barrier + QK^T + softmax.
// vmcnt bookkeeping (issue order per iter: loadK(+4) ... stageV(+4)):
//   top of iter:       out = K(kt)4 + V(kt)4  -> vmcnt(4) drains K(kt)
//   post-softmax:      out = V(kt)4 + K(kt+1)4 -> vmcnt(4) drains V(kt)
//                      (last iter: no K prefetch -> vmcnt(0))
__global__ __launch_bounds__(256, 3) void attn(const bf16* __restrict__ Qg,
                                               const bf16* __restrict__ Kg,
                                               const bf16* __restrict__ VgT,
                                               bf16* __restrict__ Yg) {
  __shared__ __align__(16) bf16 Kl[64 * 128];
  __shared__ __align__(16) bf16 Vl[128 * 64];
  __shared__ __align__(16) bf16 Pl[4 * 16 * 72];
  const int bh = blockIdx.x;
  const int qt = (int)gridDim.y - 1 - (int)blockIdx.y;  // long blocks first
  const int b = bh >> 4, h = bh & 15;
  const int tid = threadIdx.x, wave = tid >> 6, lane = tid & 63;
  const int quad = lane >> 4, li = lane & 15;
  const int q0 = qt * 64;

  // Q fragments (A-layout) straight from global, held for whole block
  const bf16* Qbase = Qg + ((size_t)bh * Tt + q0 + wave * 16 + li) * Dd;
  bf16x8 qf[4];
#pragma unroll
  for (int kc = 0; kc < 4; ++kc) qf[kc] = *(const bf16x8*)(Qbase + kc * 32 + quad * 8);

  f32x4 o[8] = {};
  float L[4] = {};
  bf16* Pw = &Pl[wave * 16 * 72];

  bf16x8 kreg[4];
  auto loadK = [&](int k0) {      // K tile [64 k][128 d] -> regs, swizzled src
#pragma unroll
    for (int j = 0; j < 4; ++j) {
      int c = j * 256 + tid;
      int r = c >> 4, cc = c & 15;
      kreg[j] = *(const bf16x8*)(Kg + ((size_t)bh * Tt + k0 + r) * Dd + ((cc ^ (r & 7)) << 3));
    }
  };
  auto stageV = [&](int k0) {     // V^T tile [128 d][64 k] -> LDS, swizzled src
#pragma unroll
    for (int j = 0; j < 4; ++j) {
      int c = j * 256 + tid;
      int r = c >> 3, cc = c & 7;
      gl_lds16(VgT + ((size_t)bh * Dd + r) * Tt + k0 + ((cc ^ (r & 7)) << 3), &Vl[c * 8]);
    }
  };

  loadK(0);       // 4 vmem
  stageV(0);      // 4 vmem

  for (int kt = 0; kt <= qt; ++kt) {
    // ---- K regs ready (drain K(kt); V(kt)'s 4 remain in flight)
    asm volatile("s_waitcnt vmcnt(4)" ::: "memory");
#pragma unroll
    for (int j = 0; j < 4; ++j) {   // reg -> LDS (conflict-free: lane*16B)
      int c = j * 256 + tid;
      *(bf16x8*)&Kl[c * 8] = kreg[j];
    }
    if (kt < qt) loadK(kt * 64 + 64);            // prefetch next K
    asm volatile("s_waitcnt lgkmcnt(0)" ::: "memory");
    __builtin_amdgcn_s_barrier();                // Kl visible to all waves
    __builtin_amdgcn_sched_barrier(0);

    // ---- QK^T
    f32x4 s4[4] = {};
#pragma unroll
    for (int nt = 0; nt < 4; ++nt) {
      int key = nt * 16 + li;
#pragma unroll
      for (int kc = 0; kc < 4; ++kc) {
        bf16x8 kf = *(const bf16x8*)&Kl[key * 128 + (((kc * 4 + quad) ^ (key & 7)) << 3)];
        s4[nt] = __builtin_amdgcn_mfma_f32_16x16x32_bf16(qf[kc], kf, s4[nt], 0, 0, 0);
      }
    }
    // ---- exp (no max needed: |s|<=1.01), mask, per-lane L, pack P
    const bool diag = (kt == qt);
#pragma unroll
    for (int nt = 0; nt < 4; ++nt)
#pragma unroll
      for (int r = 0; r < 4; ++r) {
        float e = __expf(s4[nt][r] * SCALE);
        if (diag && (nt * 16 + li > wave * 16 + quad * 4 + r)) e = 0.f;
        L[r] += e;
        Pw[(quad * 4 + r) * 72 + nt * 16 + li] = (bf16)e;
      }
    // ---- V resident (drain V(kt); K(kt+1) prefetch stays in flight)
    if (kt < qt) { asm volatile("s_waitcnt vmcnt(4)" ::: "memory"); }
    else         { asm volatile("s_waitcnt vmcnt(0)" ::: "memory"); }
    __builtin_amdgcn_s_barrier();                // Vl visible; QK^T reads done
    __builtin_amdgcn_sched_barrier(0);

    // ---- PV: o[16 q][128 d] += P[16][64] * V[64][128]
#pragma unroll
    for (int kc = 0; kc < 2; ++kc) {
      bf16x8 pf = *(const bf16x8*)&Pw[li * 72 + kc * 32 + quad * 8];
#pragma unroll
      for (int u = 0; u < 8; ++u) {
        bf16x8 vf = *(const bf16x8*)&Vl[(u * 16 + li) * 64 + (((kc * 4 + quad) ^ (li & 7)) << 3)];
        o[u] = __builtin_amdgcn_mfma_f32_16x16x32_bf16(pf, vf, o[u], 0, 0, 0);
      }
    }
    asm volatile("" ::: "memory");               // pin PV ds_reads above barrier
    __builtin_amdgcn_s_barrier();                // all waves done with Vl
    __builtin_amdgcn_sched_barrier(0);
    if (kt < qt) stageV(kt * 64 + 64);           // prefetch next V into freed Vl
  }

  // single final row-sum reduction (width 16) + normalize + write
  float inv[4];
#pragma unroll
  for (int r = 0; r < 4; ++r) {
    float s0 = L[r];
#pragma unroll
    for (int off = 1; off < 16; off <<= 1) s0 += __shfl_xor(s0, off);
    inv[r] = 1.0f / s0;
  }
  int trow = q0 + wave * 16 + quad * 4;
#pragma unroll
  for (int u = 0; u < 8; ++u) {
    int col = h * Dd + u * 16 + li;
#pragma unroll
    for (int r = 0; r < 4; ++r)
      Yg[(size_t)(b * Tt + trow + r) * Cc_ + col] = (bf16)(o[u][r] * inv[r]);
  }
}

// ------------------------------------------------------------------ launch
extern "C" void kernel_launch(void* const* d_in, const int* in_sizes, int n_in,
                              void* d_out, int out_size, void* d_ws, size_t ws_size,
                              hipStream_t stream) {
  const float* x      = (const float*)d_in[0];
  const float* w_qkv  = (const float*)d_in[1];
  const float* w_proj = (const float*)d_in[2];
  const float* qnw    = (const float*)d_in[3];
  const float* knw    = (const float*)d_in[4];
  float* out = (float*)d_out;

  // workspace partition (bf16 elements)
  bf16* xb     = (bf16*)d_ws;                   // dead after qkv GEMM
  bf16* wqkvT  = xb + (size_t)Mm_ * Cc_;
  bf16* wprojT = wqkvT + (size_t)N1 * Cc_;
  bf16* qkv    = wprojT + (size_t)Cc_ * Cc_;    // dead after norm_rope
  bf16* Qg     = qkv + (size_t)Mm_ * N1;
  bf16* Kg     = Qg + (size_t)Bb * Hh * Tt * Dd;
  bf16* Vg     = Kg + (size_t)Bb * Hh * Tt * Dd;
  bf16* VgT    = xb;    // alias: exactly xb's size
  bf16* Yg     = qkv;   // alias into qkv's region

  hipLaunchKernelGGL(cvt_bf16, dim3((Mm_ * Cc_ / 4) / 256), dim3(256), 0, stream,
                     x, xb, Mm_ * Cc_);
  hipLaunchKernelGGL(transpose_cvt, dim3(N1 / 64, Cc_ / 64), dim3(256), 0, stream,
                     w_qkv, wqkvT, Cc_, N1);
  hipLaunchKernelGGL(transpose_cvt, dim3(Cc_ / 64, Cc_ / 64), dim3(256), 0, stream,
                     w_proj, wprojT, Cc_, Cc_);
  hipLaunchKernelGGL(gemm_bf16<bf16>, dim3(N1 / 128, Mm_ / 128), dim3(256), 0, stream,
                     xb, wqkvT, qkv, N1, Cc_);
  hipLaunchKernelGGL(norm_rope_rearrange, dim3(Bb * Tt * Hh / 4), dim3(256), 0, stream,
                     qkv, qnw, knw, Qg, Kg, Vg);
  hipLaunchKernelGGL(vtrans, dim3(Tt / 64, Dd / 64, Bb * Hh), dim3(256), 0, stream,
                     Vg, VgT);
  hipLaunchKernelGGL(attn, dim3(Bb * Hh, Tt / 64), dim3(256), 0, stream,
                     Qg, Kg, VgT, Yg);
  hipLaunchKernelGGL(gemm_bf16<float>, dim3(Cc_ / 128, Mm_ / 128), dim3(256), 0, stream,
                     Yg, wprojT, out, Cc_, Cc_);
}

// Round 4
// 376.606 us; speedup vs baseline: 1.0909x; 1.0117x over previous
//
#include <hip/hip_runtime.h>
#include <stdint.h>

#define Bb   2
#define Tt   2048
#define Cc_  2048
#define Hh   16
#define Dd   128
#define Mm_  4096            // B*T
#define N1   6144            // 3*C
#define EPSf 1.1920929e-07f
#define SCALE (1.0f/128.0f)  // reference uses 1/D, not 1/sqrt(D)

typedef __bf16 bf16;
typedef __attribute__((ext_vector_type(8))) __bf16 bf16x8;
typedef __attribute__((ext_vector_type(4))) float  f32x4;

// ---- async global->LDS, width 16. LDS dest = wave-uniform base + lane*16.
__device__ __forceinline__ void gl_lds16(const bf16* g, bf16* l) {
  __builtin_amdgcn_global_load_lds(
      (const __attribute__((address_space(1))) unsigned int*)g,
      (__attribute__((address_space(3))) unsigned int*)l, 16, 0, 0);
}

// ------------------------------------------------------------------ cvt x->bf16
__global__ __launch_bounds__(256) void cvt_bf16(const float* __restrict__ in,
                                                bf16* __restrict__ out, int n) {
  int i = (blockIdx.x * 256 + threadIdx.x) * 4;
  if (i >= n) return;
  float4 v = *(const float4*)(in + i);
  union { bf16 h[4]; uint2 u; } o;
  o.h[0] = (bf16)v.x; o.h[1] = (bf16)v.y; o.h[2] = (bf16)v.z; o.h[3] = (bf16)v.w;
  *(uint2*)(out + i) = o.u;
}

// -------------------------------------------- transpose+convert: [R][Cc]f32 -> [Cc][R]bf16
__global__ __launch_bounds__(256) void transpose_cvt(const float* __restrict__ in,
                                                     bf16* __restrict__ out,
                                                     int R, int Cc) {
  __shared__ float tile[64][65];
  int c0 = blockIdx.x * 64, r0 = blockIdx.y * 64;
  int tid = threadIdx.x;
#pragma unroll
  for (int j = 0; j < 16; ++j) {
    int idx = tid + j * 256;
    int r = idx >> 6, c = idx & 63;
    tile[r][c] = in[(size_t)(r0 + r) * Cc + c0 + c];
  }
  __syncthreads();
#pragma unroll
  for (int j = 0; j < 16; ++j) {
    int idx = tid + j * 256;
    int rr = idx & 63, cc = idx >> 6;
    out[(size_t)(c0 + cc) * R + r0 + rr] = (bf16)tile[rr][cc];
  }
}

// ----------------------------------- V transpose: [bh][T][D] -> [bh][D][T] bf16
__global__ __launch_bounds__(256) void vtrans(const bf16* __restrict__ V,
                                              bf16* __restrict__ Vt_) {
  __shared__ bf16 tile[64][72];
  int bh = blockIdx.z, t0 = blockIdx.x * 64, d0 = blockIdx.y * 64;
  int tid = threadIdx.x;
#pragma unroll
  for (int j = 0; j < 2; ++j) {
    int idx = (j * 256 + tid) * 8;
    int r = idx >> 6, c = idx & 63;
    bf16x8 v = *(const bf16x8*)(V + ((size_t)bh * Tt + t0 + r) * Dd + d0 + c);
#pragma unroll
    for (int e = 0; e < 8; ++e) tile[r][c + e] = v[e];
  }
  __syncthreads();
#pragma unroll
  for (int j = 0; j < 2; ++j) {
    int idx = (j * 256 + tid) * 8;
    int dd = idx >> 6, tt = idx & 63;
    bf16x8 v;
#pragma unroll
    for (int e = 0; e < 8; ++e) v[e] = tile[tt + e][dd];
    *(bf16x8*)(Vt_ + ((size_t)bh * Dd + d0 + dd) * Tt + t0 + tt) = v;
  }
}

// ------------------------------------------------------------------ GEMM 128^2 (reference fallback; unused)
template <typename OutT>
__global__ __launch_bounds__(256) void gemm_bf16(const bf16* __restrict__ A,
                                                 const bf16* __restrict__ Bt,
                                                 OutT* __restrict__ Cm,
                                                 int Nn, int Kk) {
  __shared__ __align__(16) bf16 As[128 * 64];
  __shared__ __align__(16) bf16 Bs[128 * 64];
  const int tid = threadIdx.x;
  const int wave = tid >> 6, lane = tid & 63;
  const int quad = lane >> 4, li = lane & 15;
  const int wm = wave >> 1, wn = wave & 1;
  const int m0 = blockIdx.y * 128, n0 = blockIdx.x * 128;

  f32x4 acc[4][4] = {};

  for (int kt = 0; kt < Kk; kt += 64) {
    __syncthreads();
#pragma unroll
    for (int j = 0; j < 4; ++j) {
      int c = j * 256 + tid;
      int r = c >> 3, cc = c & 7;
      int gc = ((cc ^ (r & 7)) << 3);
      gl_lds16(A + (size_t)(m0 + r) * Kk + kt + gc, &As[c * 8]);
      gl_lds16(Bt + (size_t)(n0 + r) * Kk + kt + gc, &Bs[c * 8]);
    }
    __syncthreads();
#pragma unroll
    for (int kc = 0; kc < 2; ++kc) {
      bf16x8 af[4], bfr[4];
#pragma unroll
      for (int t = 0; t < 4; ++t) {
        int rowa = wm * 64 + t * 16 + li;
        af[t] = *(const bf16x8*)&As[rowa * 64 + (((kc * 4 + quad) ^ (rowa & 7)) << 3)];
        int rowb = wn * 64 + t * 16 + li;
        bfr[t] = *(const bf16x8*)&Bs[rowb * 64 + (((kc * 4 + quad) ^ (rowb & 7)) << 3)];
      }
#pragma unroll
      for (int mi = 0; mi < 4; ++mi)
#pragma unroll
        for (int ni = 0; ni < 4; ++ni)
          acc[mi][ni] = __builtin_amdgcn_mfma_f32_16x16x32_bf16(af[mi], bfr[ni],
                                                                acc[mi][ni], 0, 0, 0);
    }
  }
#pragma unroll
  for (int mi = 0; mi < 4; ++mi) {
    int row = m0 + wm * 64 + mi * 16 + quad * 4;
#pragma unroll
    for (int ni = 0; ni < 4; ++ni) {
      int col = n0 + wn * 64 + ni * 16 + li;
#pragma unroll
      for (int r = 0; r < 4; ++r)
        Cm[(size_t)(row + r) * Nn + col] = (OutT)acc[mi][ni][r];
    }
  }
}

// ------------------------------------------------------------------ GEMM 256x128, 8-wave
// 2 phases per K-tile (BK=64), counted vmcnt(6), phase-gated (round-2 framework).
// Wave grid 2(M)x4(N): wave = 128 rows x 32 cols, acc[8][2].
// A halves by row-bit6 (P0 reads mi 0..3, P1 reads mi 4..7); B staged whole.
//   P0: rd A0+B (12 ds_reads); stage A1(t+1)->nxt  [A1(nxt) last read t-1.P1]
//   P1: rd A1    (8 ds_reads); stage A0(t+2)->cur, B(t+2)->cur [last read P0]
// vmcnt(6) at END of each phase, before the barrier:
//   end P0: newest6 = {A0(t+1),B(t+1) (t-1.P1), A1(t+1) (t.P0)} -> A1(t) landed
//   end P1: newest6 = {A1(t+1) (t.P0), A0(t+2),B(t+2) (t.P1)} -> A0/B(t+1) landed
// Same-region stage is always >=1 lgkmcnt(0)+barrier after its last read.
// Requires M%256==0, N%128==0, K%128==0, (gx*gy)%8==0.
template <typename OutT>
__global__ __launch_bounds__(512, 2) void gemm256(const bf16* __restrict__ A,
                                                  const bf16* __restrict__ Bt,
                                                  OutT* __restrict__ Cm,
                                                  int Nn, int Kk) {
  __shared__ __align__(16) bf16 As[2][256 * 64];
  __shared__ __align__(16) bf16 Bs[2][128 * 64];
  const int tid = threadIdx.x;
  const int wave = tid >> 6, lane = tid & 63;
  const int quad = lane >> 4, li = lane & 15;
  const int wm = wave >> 2, wn = wave & 3;  // 2(M) x 4(N)

  // XCD-aware bijective swizzle (all call sites have nwg % 8 == 0)
  const int nwg = gridDim.x * gridDim.y;
  const int wg  = blockIdx.y * gridDim.x + blockIdx.x;
  const int swz = (wg & 7) * (nwg >> 3) + (wg >> 3);
  const int m0 = (swz / gridDim.x) * 256;
  const int n0 = (swz % gridDim.x) * 128;

  const int NT = Kk >> 6;
  const int lrow = lane >> 3;           // row within an 8-row segment
  const int lchk = (lane & 7) ^ lrow;   // pre-swizzled source chunk

  auto stageA = [&](int tt, int h, int cb) {   // one 128-row half (bit6==h)
    int kt = (tt < NT ? tt : NT - 1) << 6;
#pragma unroll
    for (int j = 0; j < 2; ++j) {
      int seg = j * 8 + wave;
      int r0 = ((seg >> 3) << 7) + (h << 6) + ((seg & 7) << 3);
      gl_lds16(A + (size_t)(m0 + r0 + lrow) * Kk + kt + (lchk << 3),
               &As[cb][r0 * 64]);
    }
  };
  auto stageB = [&](int tt, int cb) {          // full 128-row B tile
    int kt = (tt < NT ? tt : NT - 1) << 6;
#pragma unroll
    for (int j = 0; j < 2; ++j) {
      int seg = j * 8 + wave;
      int r0 = seg << 3;
      gl_lds16(Bt + (size_t)(n0 + r0 + lrow) * Kk + kt + (lchk << 3),
               &Bs[cb][r0 * 64]);
    }
  };

  f32x4 acc[8][2] = {};
  bf16x8 afr[4][2], bfr[2][2];

  auto rdA = [&](int h, int cb) {
#pragma unroll
    for (int mi = 0; mi < 4; ++mi) {
      int r = wm * 128 + h * 64 + mi * 16 + li;
#pragma unroll
      for (int kc = 0; kc < 2; ++kc)
        afr[mi][kc] = *(const bf16x8*)&As[cb][r * 64 + (((kc * 4 + quad) ^ (r & 7)) << 3)];
    }
  };
  auto rdB = [&](int cb) {
#pragma unroll
    for (int nj = 0; nj < 2; ++nj) {
      int r = wn * 32 + nj * 16 + li;
#pragma unroll
      for (int kc = 0; kc < 2; ++kc)
        bfr[nj][kc] = *(const bf16x8*)&Bs[cb][r * 64 + (((kc * 4 + quad) ^ (r & 7)) << 3)];
    }
  };
  auto mmac = [&](int mo) {
    __builtin_amdgcn_s_setprio(1);
#pragma unroll
    for (int kc = 0; kc < 2; ++kc)
#pragma unroll
      for (int mi = 0; mi < 4; ++mi)
#pragma unroll
        for (int nj = 0; nj < 2; ++nj)
          acc[mo + mi][nj] = __builtin_amdgcn_mfma_f32_16x16x32_bf16(
              afr[mi][kc], bfr[nj][kc], acc[mo + mi][nj], 0, 0, 0);
    __builtin_amdgcn_s_setprio(0);
  };

  auto tile = [&](int t, int cur, int nxt) {
    // ---- P0: A0 x B (12 ds_reads; stage A1(t+1)->nxt)
    rdA(0, cur); rdB(cur);
    stageA(t + 1, 1, nxt);
    asm volatile("s_waitcnt lgkmcnt(8)" ::: "memory");  // throttle heavy phase
    __builtin_amdgcn_s_barrier();
    asm volatile("s_waitcnt lgkmcnt(0)" ::: "memory");
    __builtin_amdgcn_sched_barrier(0);
    mmac(0);
    asm volatile("s_waitcnt vmcnt(6)" ::: "memory");
    __builtin_amdgcn_s_barrier();
    // ---- P1: A1 x B (8 ds_reads; stage A0(t+2)->cur, B(t+2)->cur)
    rdA(1, cur);
    stageA(t + 2, 0, cur);
    stageB(t + 2, cur);
    __builtin_amdgcn_s_barrier();
    asm volatile("s_waitcnt lgkmcnt(0)" ::: "memory");
    __builtin_amdgcn_sched_barrier(0);
    mmac(4);
    asm volatile("s_waitcnt vmcnt(6)" ::: "memory");
    __builtin_amdgcn_s_barrier();
  };

  // prologue: tile0 {A0,B,A1}->buf0, tile1 {A0,B}->buf1; vmcnt(6) -> A0(0),B(0) resident
  stageA(0, 0, 0); stageB(0, 0); stageA(0, 1, 0);
  stageA(1, 0, 1); stageB(1, 1);
  asm volatile("s_waitcnt vmcnt(6)" ::: "memory");
  __builtin_amdgcn_s_barrier();

  for (int t = 0; t < NT; t += 2) {   // K % 128 == 0
    tile(t, 0, 1);
    tile(t + 1, 1, 0);
  }
  // drain tail stages before LDS is released at endpgm
  asm volatile("s_waitcnt vmcnt(0)" ::: "memory");

#pragma unroll
  for (int mi = 0; mi < 8; ++mi) {
    int row = m0 + wm * 128 + mi * 16 + quad * 4;
#pragma unroll
    for (int nj = 0; nj < 2; ++nj) {
      int col = n0 + wn * 32 + nj * 16 + li;
#pragma unroll
      for (int r = 0; r < 4; ++r)
        Cm[(size_t)(row + r) * Nn + col] = (OutT)acc[mi][nj][r];
    }
  }
}

// ------------------------------------------- RMSNorm + RoPE + rearrange
__global__ __launch_bounds__(256) void norm_rope_rearrange(
    const bf16* __restrict__ qkv, const float* __restrict__ qw,
    const float* __restrict__ kw, bf16* __restrict__ Qg,
    bf16* __restrict__ Kg, bf16* __restrict__ Vg) {
  int unit = blockIdx.x * 4 + (threadIdx.x >> 6);  // (b*T + t)*H + h
  int lane = threadIdx.x & 63;
  int h = unit & 15;
  int bt = unit >> 4;
  int t = bt & 2047, b = bt >> 11;
  const bf16* base = qkv + (size_t)bt * N1 + h * Dd;
  float q1 = (float)base[lane], q2 = (float)base[lane + 64];
  float k1 = (float)base[Cc_ + lane], k2 = (float)base[Cc_ + lane + 64];
  float v1 = (float)base[2 * Cc_ + lane], v2 = (float)base[2 * Cc_ + lane + 64];
  float sq = q1 * q1 + q2 * q2;
  float sk = k1 * k1 + k2 * k2;
#pragma unroll
  for (int o = 1; o < 64; o <<= 1) { sq += __shfl_xor(sq, o); sk += __shfl_xor(sk, o); }
  float rq = rsqrtf(sq * (1.0f / 128.0f) + EPSf);
  float rk = rsqrtf(sk * (1.0f / 128.0f) + EPSf);
  q1 *= rq * qw[lane]; q2 *= rq * qw[lane + 64];
  k1 *= rk * kw[lane]; k2 *= rk * kw[lane + 64];
  float invf = exp2f((float)lane * (-19.9315685693241740f / 64.0f));
  float ang = (float)t * invf;
  float sn, cs;
  sincosf(ang, &sn, &cs);
  float qo1 = q1 * cs - q2 * sn, qo2 = q2 * cs + q1 * sn;
  float ko1 = k1 * cs - k2 * sn, ko2 = k2 * cs + k1 * sn;
  size_t o1 = ((size_t)(b * Hh + h) * Tt + t) * Dd + lane;
  Qg[o1] = (bf16)qo1; Qg[o1 + 64] = (bf16)qo2;
  Kg[o1] = (bf16)ko1; Kg[o1 + 64] = (bf16)ko2;
  Vg[o1] = (bf16)v1;  Vg[o1 + 64] = (bf16)v2;
}

// ------------------------------------------------------------------ attention
// Single q-tile per block, grid 32bh x 32qt (qt descending), 1024 blocks.
// Exact-bound softmax: q,k RMS-normed (w=1) + RoPE norm-preserving + scale
// 1/128 => |s| <= ~1.01 (Cauchy-Schwarz). No max tracking, no o-rescale;
// L accumulated per-lane, reduced ONCE at the end.
//
// T14 async-staged pipeline (no LDS growth, occupancy stays 3/CU):
//   K(kt):  global->reg during iter kt-1; reg->LDS ds_write at top of iter kt.
//   V(kt):  gl_lds issued at END of iter kt-1 (after PV-done barrier).
// vmcnt: top of iter vmcnt(4) drains K(kt); post-softmax vmcnt(4) drains V(kt)
//        (last iter: vmcnt(0)).
__global__ __launch_bounds__(256, 3) void attn(const bf16* __restrict__ Qg,
                                               const bf16* __restrict__ Kg,
                                               const bf16* __restrict__ VgT,
                                               bf16* __restrict__ Yg) {
  __shared__ __align__(16) bf16 Kl[64 * 128];
  __shared__ __align__(16) bf16 Vl[128 * 64];
  __shared__ __align__(16) bf16 Pl[4 * 16 * 72];
  const int bh = blockIdx.x;
  const int qt = (int)gridDim.y - 1 - (int)blockIdx.y;  // long blocks first
  const int b = bh >> 4, h = bh & 15;
  const int tid = threadIdx.x, wave = tid >> 6, lane = tid & 63;
  const int quad = lane >> 4, li = lane & 15;
  const int q0 = qt * 64;

  // Q fragments (A-layout) straight from global, held for whole block
  const bf16* Qbase = Qg + ((size_t)bh * Tt + q0 + wave * 16 + li) * Dd;
  bf16x8 qf[4];
#pragma unroll
  for (int kc = 0; kc < 4; ++kc) qf[kc] = *(const bf16x8*)(Qbase + kc * 32 + quad * 8);

  f32x4 o[8] = {};
  float L[4] = {};
  bf16* Pw = &Pl[wave * 16 * 72];

  bf16x8 kreg[4];
  auto loadK = [&](int k0) {      // K tile [64 k][128 d] -> regs, swizzled src
#pragma unroll
    for (int j = 0; j < 4; ++j) {
      int c = j * 256 + tid;
      int r = c >> 4, cc = c & 15;
      kreg[j] = *(const bf16x8*)(Kg + ((size_t)bh * Tt + k0 + r) * Dd + ((cc ^ (r & 7)) << 3));
    }
  };
  auto stageV = [&](int k0) {     // V^T tile [128 d][64 k] -> LDS, swizzled src
#pragma unroll
    for (int j = 0; j < 4; ++j) {
      int c = j * 256 + tid;
      int r = c >> 3, cc = c & 7;
      gl_lds16(VgT + ((size_t)bh * Dd + r) * Tt + k0 + ((cc ^ (r & 7)) << 3), &Vl[c * 8]);
    }
  };

  loadK(0);       // 4 vmem
  stageV(0);      // 4 vmem

  for (int kt = 0; kt <= qt; ++kt) {
    // ---- K regs ready (drain K(kt); V(kt)'s 4 remain in flight)
    asm volatile("s_waitcnt vmcnt(4)" ::: "memory");
#pragma unroll
    for (int j = 0; j < 4; ++j) {   // reg -> LDS (conflict-free: lane*16B)
      int c = j * 256 + tid;
      *(bf16x8*)&Kl[c * 8] = kreg[j];
    }
    if (kt < qt) loadK(kt * 64 + 64);            // prefetch next K
    asm volatile("s_waitcnt lgkmcnt(0)" ::: "memory");
    __builtin_amdgcn_s_barrier();                // Kl visible to all waves
    __builtin_amdgcn_sched_barrier(0);

    // ---- QK^T
    f32x4 s4[4] = {};
#pragma unroll
    for (int nt = 0; nt < 4; ++nt) {
      int key = nt * 16 + li;
#pragma unroll
      for (int kc = 0; kc < 4; ++kc) {
        bf16x8 kf = *(const bf16x8*)&Kl[key * 128 + (((kc * 4 + quad) ^ (key & 7)) << 3)];
        s4[nt] = __builtin_amdgcn_mfma_f32_16x16x32_bf16(qf[kc], kf, s4[nt], 0, 0, 0);
      }
    }
    // ---- exp (no max needed: |s|<=1.01), mask, per-lane L, pack P
    const bool diag = (kt == qt);
#pragma unroll
    for (int nt = 0; nt < 4; ++nt)
#pragma unroll
      for (int r = 0; r < 4; ++r) {
        float e = __expf(s4[nt][r] * SCALE);
        if (diag && (nt * 16 + li > wave * 16 + quad * 4 + r)) e = 0.f;
        L[r] += e;
        Pw[(quad * 4 + r) * 72 + nt * 16 + li] = (bf16)e;
      }
    // ---- V resident (drain V(kt); K(kt+1) prefetch stays in flight)
    if (kt < qt) { asm volatile("s_waitcnt vmcnt(4)" ::: "memory"); }
    else         { asm volatile("s_waitcnt vmcnt(0)" ::: "memory"); }
    __builtin_amdgcn_s_barrier();                // Vl visible; QK^T reads done
    __builtin_amdgcn_sched_barrier(0);

    // ---- PV: o[16 q][128 d] += P[16][64] * V[64][128]
#pragma unroll
    for (int kc = 0; kc < 2; ++kc) {
      bf16x8 pf = *(const bf16x8*)&Pw[li * 72 + kc * 32 + quad * 8];
#pragma unroll
      for (int u = 0; u < 8; ++u) {
        bf16x8 vf = *(const bf16x8*)&Vl[(u * 16 + li) * 64 + (((kc * 4 + quad) ^ (li & 7)) << 3)];
        o[u] = __builtin_amdgcn_mfma_f32_16x16x32_bf16(pf, vf, o[u], 0, 0, 0);
      }
    }
    asm volatile("" ::: "memory");               // pin PV ds_reads above barrier
    __builtin_amdgcn_s_barrier();                // all waves done with Vl
    __builtin_amdgcn_sched_barrier(0);
    if (kt < qt) stageV(kt * 64 + 64);           // prefetch next V into freed Vl
  }

  // single final row-sum reduction (width 16) + normalize + write
  float inv[4];
#pragma unroll
  for (int r = 0; r < 4; ++r) {
    float s0 = L[r];
#pragma unroll
    for (int off = 1; off < 16; off <<= 1) s0 += __shfl_xor(s0, off);
    inv[r] = 1.0f / s0;
  }
  int trow = q0 + wave * 16 + quad * 4;
#pragma unroll
  for (int u = 0; u < 8; ++u) {
    int col = h * Dd + u * 16 + li;
#pragma unroll
    for (int r = 0; r < 4; ++r)
      Yg[(size_t)(b * Tt + trow + r) * Cc_ + col] = (bf16)(o[u][r] * inv[r]);
  }
}

// ------------------------------------------------------------------ launch
extern "C" void kernel_launch(void* const* d_in, const int* in_sizes, int n_in,
                              void* d_out, int out_size, void* d_ws, size_t ws_size,
                              hipStream_t stream) {
  const float* x      = (const float*)d_in[0];
  const float* w_qkv  = (const float*)d_in[1];
  const float* w_proj = (const float*)d_in[2];
  const float* qnw    = (const float*)d_in[3];
  const float* knw    = (const float*)d_in[4];
  float* out = (float*)d_out;

  // workspace partition (bf16 elements)
  bf16* xb     = (bf16*)d_ws;                   // dead after qkv GEMM
  bf16* wqkvT  = xb + (size_t)Mm_ * Cc_;
  bf16* wprojT = wqkvT + (size_t)N1 * Cc_;
  bf16* qkv    = wprojT + (size_t)Cc_ * Cc_;    // dead after norm_rope
  bf16* Qg     = qkv + (size_t)Mm_ * N1;
  bf16* Kg     = Qg + (size_t)Bb * Hh * Tt * Dd;
  bf16* Vg     = Kg + (size_t)Bb * Hh * Tt * Dd;
  bf16* VgT    = xb;    // alias: exactly xb's size
  bf16* Yg     = qkv;   // alias into qkv's region

  hipLaunchKernelGGL(cvt_bf16, dim3((Mm_ * Cc_ / 4) / 256), dim3(256), 0, stream,
                     x, xb, Mm_ * Cc_);
  hipLaunchKernelGGL(transpose_cvt, dim3(N1 / 64, Cc_ / 64), dim3(256), 0, stream,
                     w_qkv, wqkvT, Cc_, N1);
  hipLaunchKernelGGL(transpose_cvt, dim3(Cc_ / 64, Cc_ / 64), dim3(256), 0, stream,
                     w_proj, wprojT, Cc_, Cc_);
  // QKV GEMM: 256x128 tile -> 48x16 = 768 wg = 3 clean rounds at 1 block/CU
  hipLaunchKernelGGL(gemm256<bf16>, dim3(N1 / 128, Mm_ / 256), dim3(512), 0, stream,
                     xb, wqkvT, qkv, N1, Cc_);
  hipLaunchKernelGGL(norm_rope_rearrange, dim3(Bb * Tt * Hh / 4), dim3(256), 0, stream,
                     qkv, qnw, knw, Qg, Kg, Vg);
  hipLaunchKernelGGL(vtrans, dim3(Tt / 64, Dd / 64, Bb * Hh), dim3(256), 0, stream,
                     Vg, VgT);
  hipLaunchKernelGGL(attn, dim3(Bb * Hh, Tt / 64), dim3(256), 0, stream,
                     Qg, Kg, VgT, Yg);
  // proj GEMM: 16x16 = 256 wg = exactly 1 round
  hipLaunchKernelGGL(gemm256<float>, dim3(Cc_ / 128, Mm_ / 256), dim3(512), 0, stream,
                     Yg, wprojT, out, Cc_, Cc_);
}